// Round 1
// baseline (25751.721 us; speedup 1.0000x reference)
//
#include <hip/hip_runtime.h>

#define BB 128
#define TT 256
#define HH 512
#define GG 2048
#define KT 64

__device__ __forceinline__ float fsig(float x) { return 1.f / (1.f + __expf(-x)); }

// One LSTM timestep for up to 2 directions (blockIdx.y = dir).
// gates[b][g] = bias[g] + sum_k xin[b][k]*wih[g][k] + sum_k h_prev[b][k]*whh[g][k]
// Block: 256 threads, computes 16 hidden units (64 gate rows) x 16 batch.
// grid.x = 32 hidden-tiles * 8 batch-tiles = 256.
template <int K1>
__global__ __launch_bounds__(256) void lstm_step(
    int s, int reverse_mask,
    const float* __restrict__ xF, const float* __restrict__ xB,
    long x_bs, long x_ts,
    const float* __restrict__ wihF, const float* __restrict__ wihB,
    const float* __restrict__ whhF, const float* __restrict__ whhB,
    const float* __restrict__ bF, const float* __restrict__ bB,
    const float* __restrict__ h_prev, float* __restrict__ h_next,
    float* __restrict__ c_state,
    float* __restrict__ h_out)  // [B][T][1024] at [b][t][d*512+j], may be null
{
  const int d = blockIdx.y;
  const int t = ((reverse_mask >> d) & 1) ? (TT - 1 - s) : s;
  const float* xin = (d ? xB : xF) + (long)t * x_ts;
  const float* wih = d ? wihB : wihF;
  const float* whh = d ? whhB : whhF;
  const float* bias = d ? bB : bF;
  const float* hp = h_prev + (long)d * (BB * HH);
  float* hn = h_next + (long)d * (BB * HH);
  float* cs = c_state + (long)d * (BB * HH);

  const int ht = blockIdx.x & 31;  // hidden tile (32 tiles of 16)
  const int bt = blockIdx.x >> 5;  // batch tile (8 tiles of 16)
  const int j0 = ht * 16;
  const int b0 = bt * 16;

  const int tid = threadIdx.x;
  const int rr = tid & 63;   // lane: q*16 + jj
  const int jj = rr & 15;
  const int bg = tid >> 6;   // wave id -> batch subgroup
  const int row = (rr >> 4) * HH + j0 + jj;  // gate row in [0,2048)

  __shared__ float sh_w[64][KT + 4];
  __shared__ float sh_h[16][KT + 4];

  float acc[4] = {0.f, 0.f, 0.f, 0.f};

  // staging maps
  const int lr = tid >> 2;  // 0..63 weight row slot
  const int qt = tid & 3;   // k quarter
  const int wrow = (lr >> 4) * HH + j0 + (lr & 15);
  const int hb = tid >> 4;        // 0..15
  const int hk = (tid & 15) * 4;  // 0..60

  for (int phase = 0; phase < 2; ++phase) {
    const float* src = phase ? hp : xin;
    const float* wsrc = phase ? whh : wih;
    const long ldw = phase ? (long)HH : (long)K1;
    const long srcStride = phase ? (long)HH : x_bs;
    const int Kp = phase ? HH : K1;
    for (int k0 = 0; k0 < Kp; k0 += KT) {
      __syncthreads();  // protect LDS from previous tile's readers
      {
        const float* wr = wsrc + (long)wrow * ldw + k0 + qt * 16;
#pragma unroll
        for (int i = 0; i < 4; ++i) {
          float4 v = *(const float4*)(wr + i * 4);
          *(float4*)&sh_w[lr][qt * 16 + i * 4] = v;
        }
      }
      {
        const float* hr = src + (long)(b0 + hb) * srcStride + k0 + hk;
        float4 v = *(const float4*)hr;
        *(float4*)&sh_h[hb][hk] = v;
      }
      __syncthreads();
#pragma unroll
      for (int kk = 0; kk < KT; kk += 4) {
        float4 w4 = *(const float4*)&sh_w[rr][kk];
#pragma unroll
        for (int u = 0; u < 4; ++u) {
          float4 h4 = *(const float4*)&sh_h[bg * 4 + u][kk];
          acc[u] = fmaf(h4.x, w4.x, acc[u]);
          acc[u] = fmaf(h4.y, w4.y, acc[u]);
          acc[u] = fmaf(h4.z, w4.z, acc[u]);
          acc[u] = fmaf(h4.w, w4.w, acc[u]);
        }
      }
    }
  }

  const float bi = bias[row];
#pragma unroll
  for (int u = 0; u < 4; ++u) {
    float g = acc[u] + bi;
    // gather the 4 gate types for (jj, b_u): lanes jj, jj+16, jj+32, jj+48
    float gi = __shfl(g, jj);
    float gf = __shfl(g, jj + 16);
    float gg = __shfl(g, jj + 32);
    float go = __shfl(g, jj + 48);
    if (rr < 16) {
      const int b = b0 + bg * 4 + u;
      const long idx = (long)b * HH + (j0 + jj);
      float cn = fsig(gf) * cs[idx] + fsig(gi) * tanhf(gg);
      cs[idx] = cn;
      float hv = fsig(go) * tanhf(cn);
      hn[idx] = hv;
      if (h_out)
        h_out[(long)b * (TT * 1024) + (long)t * 1024 + d * 512 + (j0 + jj)] = hv;
    }
  }
}

__global__ void fc_kernel(const float* __restrict__ h1f, const float* __restrict__ h1b,
                          const float* __restrict__ fcw, const float* __restrict__ fcb,
                          float* __restrict__ out) {
  const int b = blockIdx.x;
  const int lane = threadIdx.x;
  float s = 0.f;
  for (int j = lane; j < HH; j += 64) {
    s += h1f[(long)b * HH + j] * fcw[j];
    s += h1b[(long)b * HH + j] * fcw[HH + j];
  }
#pragma unroll
  for (int off = 32; off; off >>= 1) s += __shfl_down(s, off);
  if (lane == 0) out[b] = s + fcb[0];
}

extern "C" void kernel_launch(void* const* d_in, const int* in_sizes, int n_in,
                              void* d_out, int out_size, void* d_ws, size_t ws_size,
                              hipStream_t stream) {
  const float* x     = (const float*)d_in[0];
  const float* wih0f = (const float*)d_in[1];
  const float* whh0f = (const float*)d_in[2];
  const float* b0f   = (const float*)d_in[3];
  const float* wih0b = (const float*)d_in[4];
  const float* whh0b = (const float*)d_in[5];
  const float* b0b   = (const float*)d_in[6];
  const float* wih1f = (const float*)d_in[7];
  const float* whh1f = (const float*)d_in[8];
  const float* b1f   = (const float*)d_in[9];
  const float* wih1b = (const float*)d_in[10];
  const float* whh1b = (const float*)d_in[11];
  const float* b1b   = (const float*)d_in[12];
  const float* fcw   = (const float*)d_in[13];
  const float* fcb   = (const float*)d_in[14];
  float* out = (float*)d_out;

  float* ws  = (float*)d_ws;
  float* hA  = ws;               // [2][128][512]
  float* hB  = hA + 2 * BB * HH; // [2][128][512]
  float* cS  = hB + 2 * BB * HH; // [2][128][512]
  float* zb  = cS + 2 * BB * HH; // [128][512] zeros
  float* cz  = zb + BB * HH;     // [128][512] zeros (scratch c for l1-bwd)
  float* h1b = cz + BB * HH;     // [128][512]
  float* h0  = h1b + BB * HH;    // [128][256][1024]  (128 MB)

  hipMemsetAsync(hA, 0, 2 * BB * HH * sizeof(float), stream);
  hipMemsetAsync(cS, 0, 2 * BB * HH * sizeof(float), stream);
  hipMemsetAsync(zb, 0, BB * HH * sizeof(float), stream);
  hipMemsetAsync(cz, 0, BB * HH * sizeof(float), stream);

  dim3 blk(256);

  // layer 0: fwd (d=0) + bwd (d=1) concurrently, reverse_mask=0b10
  for (int s = 0; s < TT; ++s) {
    const float* hp = (s & 1) ? hB : hA;
    float* hn = (s & 1) ? hA : hB;
    lstm_step<64><<<dim3(256, 2), blk, 0, stream>>>(
        s, 2, x, x, (long)TT * 64, 64,
        wih0f, wih0b, whh0f, whh0b, b0f, b0b,
        hp, hn, cS, h0);
  }

  hipMemsetAsync(hA, 0, 2 * BB * HH * sizeof(float), stream);
  hipMemsetAsync(cS, 0, 2 * BB * HH * sizeof(float), stream);

  // layer 1 forward: input = h0 [B][T][1024], only final h needed
  for (int s = 0; s < TT; ++s) {
    const float* hp = (s & 1) ? hB : hA;
    float* hn = (s & 1) ? hA : hB;
    lstm_step<1024><<<dim3(256, 1), blk, 0, stream>>>(
        s, 0, h0, nullptr, (long)TT * 1024, 1024,
        wih1f, nullptr, whh1f, nullptr, b1f, nullptr,
        hp, hn, cS, nullptr);
  }

  // layer 1 backward: output only needs its t=T-1 step (h0_prev = 0)
  lstm_step<1024><<<dim3(256, 1), blk, 0, stream>>>(
      0, 1, h0, nullptr, (long)TT * 1024, 1024,
      wih1b, nullptr, whh1b, nullptr, b1b, nullptr,
      zb, h1b, cz, nullptr);

  // fc on [h1f_final ; h1b_255]; after 256 steps (s=255 odd) final h is in hA dir0
  fc_kernel<<<dim3(BB), dim3(64), 0, stream>>>(hA, h1b, fcw, fcb, out);
}